// Round 9
// baseline (264.082 us; speedup 1.0000x reference)
//
#include <hip/hip_runtime.h>
#include <hip/hip_bf16.h>
#include <math.h>

// CausalMHA+RoPE: B=1, S=4096, DM=1024, H=16, DK=64. fp32 in / fp32 out.
// R9: attn is LDS-instruction-bound (R8: 3300 cyc/iter/CU ~= LDS inst budget).
// (1) Compute S^T (swap mfma operands): lane holds S[q=ln][key=quad*4+r] ->
//     P writes become ds_write_b64 (was 16x ds_write_b16/tile); row-sum scalar.
// (2) 4 waves x 64 rows (2 rg of tile A + 2 of tile B): K/V frag reads
//     amortized 2x; per-CU LDS traffic halves. Grid (16,16) balanced as R8.
// (3) prep launches fused 5->1.

#define SEQ 4096
#define DM  1024
#define NH  16
#define DK  64

typedef __attribute__((ext_vector_type(8))) short short8;   // 8 bf16 (MFMA A/B frag)
typedef __attribute__((ext_vector_type(4))) float floatx4;  // MFMA C/D frag
typedef __attribute__((ext_vector_type(4))) short short4v;  // 4 bf16 (8 B)

static __device__ __forceinline__ short f2bf(float f) {
    __hip_bfloat16 h = __float2bfloat16(f);
    return __builtin_bit_cast(short, h);
}

static __device__ __forceinline__ short8 load8_f32_as_bf16(const float* p) {
    float4 a = *reinterpret_cast<const float4*>(p);
    float4 b = *reinterpret_cast<const float4*>(p + 4);
    short8 s;
    s[0] = f2bf(a.x); s[1] = f2bf(a.y); s[2] = f2bf(a.z); s[3] = f2bf(a.w);
    s[4] = f2bf(b.x); s[5] = f2bf(b.y); s[6] = f2bf(b.z); s[7] = f2bf(b.w);
    return s;
}

// async global->LDS, 16 B/lane. LDS dest = wave-uniform base + lane*16.
static __device__ __forceinline__ void gl2lds16(const __hip_bfloat16* g, short* l) {
    __builtin_amdgcn_global_load_lds(
        (const __attribute__((address_space(1))) unsigned int*)g,
        (__attribute__((address_space(3))) unsigned int*)l, 16, 0, 0);
}

static __device__ __forceinline__ int read_pos(const int* tp32, int s) {
    return (tp32[1] == 1) ? tp32[s] : tp32[2 * s];
}

// ---------------------------------------------------------------------------
// Fused prep: fp32->bf16 for x/Wq/Wk/Wv + RoPE cos/sin table. Grid 4096.
// ---------------------------------------------------------------------------
__global__ __launch_bounds__(256) void prep_kernel(
    const float* __restrict__ x,  const float* __restrict__ Wq,
    const float* __restrict__ Wk, const float* __restrict__ Wv,
    const int* __restrict__ tp,
    __hip_bfloat16* __restrict__ xb,  __hip_bfloat16* __restrict__ Wqb,
    __hip_bfloat16* __restrict__ Wkb, __hip_bfloat16* __restrict__ Wvb,
    float2* __restrict__ tab)
{
    int b = blockIdx.x;
    if (b < 3584) {
        const float* src; __hip_bfloat16* dst; int off;
        if (b < 2048)      { src = x;  dst = xb;  off = b; }
        else if (b < 2560) { src = Wq; dst = Wqb; off = b - 2048; }
        else if (b < 3072) { src = Wk; dst = Wkb; off = b - 2560; }
        else               { src = Wv; dst = Wvb; off = b - 3072; }
        size_t i = (size_t)off * 256 + threadIdx.x;
        short8 v = load8_f32_as_bf16(src + i * 8);
        *reinterpret_cast<short8*>((short*)dst + i * 8) = v;
    } else {
        int idx = (b - 3584) * 256 + threadIdx.x;   // SEQ*32 entries
        if (idx < SEQ * 32) {
            int s = idx >> 5, pair = idx & 31;
            float inv_freq = exp2f(-(float)(2 * pair) * (13.287712379549449f / 64.f));
            float sn, cs;
            sincosf((float)read_pos(tp, s) * inv_freq, &sn, &cs);
            tab[idx] = make_float2(cs, sn);
        }
    }
}

// ---------------------------------------------------------------------------
// Kernel 1: QKV NT-GEMM + RoPE epilogue (unchanged from R7/R8 — verified).
// ---------------------------------------------------------------------------
__global__ __launch_bounds__(256) void qkv_rope_kernel(
    const __hip_bfloat16* __restrict__ xb,
    const float2* __restrict__ tab,
    const __hip_bfloat16* __restrict__ Wqb,
    const __hip_bfloat16* __restrict__ Wkb,
    const __hip_bfloat16* __restrict__ Wvb,
    __hip_bfloat16* __restrict__ q_ws,
    __hip_bfloat16* __restrict__ k_ws,
    __hip_bfloat16* __restrict__ vt_ws)
{
    __shared__ __align__(16) short pool[17408];
    short* As = pool;
    short* Bs = pool + 8192;

    const int by = blockIdx.y;
    const int wsel = by >> 3;
    const __hip_bfloat16* W = (wsel == 0) ? Wqb : (wsel == 1 ? Wkb : Wvb);
    const int nloc0 = (by & 7) * 128;
    const int m0 = blockIdx.x * 128;

    const int t = threadIdx.x;
    const int lane = t & 63;
    const int w = t >> 6;
    const int quad = lane >> 4;
    const int ln = lane & 15;
    const int wm = (w >> 1) * 64;
    const int wn = (w & 1) * 64;

    floatx4 acc[4][4];
    #pragma unroll
    for (int i = 0; i < 4; i++)
        #pragma unroll
        for (int j = 0; j < 4; j++) acc[i][j] = (floatx4){0.f, 0.f, 0.f, 0.f};

    for (int k0 = 0; k0 < DM; k0 += 64) {
        #pragma unroll
        for (int it = 0; it < 4; it++) {
            int row = w * 32 + it * 8 + (lane >> 3);
            int sg = (lane & 7) ^ (row & 7);
            gl2lds16(&xb[(size_t)(m0 + row) * DM + k0 + sg * 8], &As[(w * 32 + it * 8) * 64]);
            gl2lds16(&W[(size_t)(nloc0 + row) * DM + k0 + sg * 8], &Bs[(w * 32 + it * 8) * 64]);
        }
        __syncthreads();

        short8 af[4][2], bfr[4][2];
        #pragma unroll
        for (int i = 0; i < 4; i++)
            #pragma unroll
            for (int kc = 0; kc < 2; kc++)
                af[i][kc] = *reinterpret_cast<const short8*>(
                    &As[(wm + i * 16 + ln) * 64 + (((kc * 4 + quad) ^ (ln & 7)) << 3)]);
        #pragma unroll
        for (int j = 0; j < 4; j++)
            #pragma unroll
            for (int kc = 0; kc < 2; kc++)
                bfr[j][kc] = *reinterpret_cast<const short8*>(
                    &Bs[(wn + j * 16 + ln) * 64 + (((kc * 4 + quad) ^ (ln & 7)) << 3)]);

        #pragma unroll
        for (int kc = 0; kc < 2; kc++)
            #pragma unroll
            for (int i = 0; i < 4; i++)
                #pragma unroll
                for (int j = 0; j < 4; j++)
                    acc[i][j] = __builtin_amdgcn_mfma_f32_16x16x32_bf16(
                        af[i][kc], bfr[j][kc], acc[i][j], 0, 0, 0);
        __syncthreads();
    }

    if (wsel < 2) {
        __hip_bfloat16* dst = (wsel == 0) ? q_ws : k_ws;
        const float qscale = (wsel == 0) ? 0.125f : 1.0f;
        #pragma unroll
        for (int j = 0; j < 4; j++) {
            int cnl = wn + j * 16 + ln;
            int pair = ((nloc0 + cnl) & 63) >> 1;
            #pragma unroll
            for (int i = 0; i < 4; i++) {
                int rowl = wm + i * 16 + quad * 4;
                #pragma unroll
                for (int r = 0; r < 4; r++) {
                    float2 t2 = tab[(size_t)(m0 + rowl + r) * 32 + pair];
                    float val = acc[i][j][r];
                    float partner = __shfl_xor(val, 1, 64);
                    float res = val * t2.x + (((lane & 1) ? partner : -partner) * t2.y);
                    pool[(rowl + r) * 136 + cnl] = f2bf(res * qscale);
                }
            }
        }
        __syncthreads();
        int row = t >> 1, half = t & 1;
        size_t gbase = (size_t)(m0 + row) * DM + nloc0 + half * 64;
        #pragma unroll
        for (int c = 0; c < 8; c++)
            *reinterpret_cast<short8*>(&dst[gbase + c * 8]) =
                *reinterpret_cast<const short8*>(&pool[row * 136 + half * 64 + c * 8]);
    } else {
        #pragma unroll
        for (int j = 0; j < 4; j++) {
            int cnl = wn + j * 16 + ln;
            #pragma unroll
            for (int i = 0; i < 4; i++) {
                int s0 = wm + i * 16 + quad * 4;
                #pragma unroll
                for (int r = 0; r < 4; r++)
                    pool[cnl * 136 + s0 + r] = f2bf(acc[i][j][r]);
            }
        }
        __syncthreads();
        int cnl = t >> 1, sh = t & 1;
        size_t base = (size_t)(nloc0 + cnl) * SEQ + m0 + sh * 64;
        #pragma unroll
        for (int c = 0; c < 8; c++)
            *reinterpret_cast<short8*>(&vt_ws[base + c * 8]) =
                *reinterpret_cast<const short8*>(&pool[cnl * 136 + sh * 64 + c * 8]);
    }
}

// ---------------------------------------------------------------------------
// Kernel 2: causal flash attention. Grid (16,16), 256 thr = 4 waves.
// Wave owns 64 q-rows: rg0,1 = tile A (31-bx) rows w*32..+31; rg2,3 = tile B (bx).
// S^T formulation: sacc = mfma(kf, qf) -> lane holds S[q=ln][key=quad*4+r];
// P written as [q][key] row-major via ds_write_b64; PV reads unchanged (b128).
// K/V double-buffered async LDS staging, XOR-swizzled. Fixed-base softmax.
// ---------------------------------------------------------------------------
__global__ __launch_bounds__(256) void attn_kernel(
    const __hip_bfloat16* __restrict__ q_ws,
    const __hip_bfloat16* __restrict__ k_ws,
    const __hip_bfloat16* __restrict__ vt_ws,
    __hip_bfloat16* __restrict__ o_ws)   // [SEQ][DM]
{
    __shared__ __align__(16) short Kt[2][64 * 64];
    __shared__ __align__(16) short Vt[2][64 * 64];
    __shared__ __align__(16) short P[4][16 * 72];

    const int head = blockIdx.y;
    const int bx = blockIdx.x;            // 0..15
    const int qbA0 = (31 - bx) * 128;     // long tile
    const int qbB0 = bx * 128;            // short tile
    const int t = threadIdx.x;
    const int lane = t & 63;
    const int w = t >> 6;                 // 0..3
    const int quad = lane >> 4;
    const int ln = lane & 15;
    const int niter = (31 - bx) * 2 + 2;

    int rgbase[4];
    rgbase[0] = qbA0 + w * 32;
    rgbase[1] = qbA0 + w * 32 + 16;
    rgbase[2] = qbB0 + w * 32;
    rgbase[3] = qbB0 + w * 32 + 16;

    auto stage = [&](int b, int kb) {
        #pragma unroll
        for (int p = 0; p < 2; p++) {
            int row = p * 32 + w * 8 + (lane >> 3);
            int sg = (lane & 7) ^ (row & 7);
            gl2lds16(&k_ws[(size_t)(kb + row) * DM + head * 64 + sg * 8],
                     &Kt[b][(p * 32 + w * 8) * 64]);
            gl2lds16(&vt_ws[(size_t)(head * 64 + row) * SEQ + kb + sg * 8],
                     &Vt[b][(p * 32 + w * 8) * 64]);
        }
    };

    short8 qf[4][2];
    #pragma unroll
    for (int rg = 0; rg < 4; rg++)
        #pragma unroll
        for (int kk = 0; kk < 2; kk++)
            qf[rg][kk] = *reinterpret_cast<const short8*>(
                &q_ws[(size_t)(rgbase[rg] + ln) * DM + head * 64 + kk * 32 + quad * 8]);

    floatx4 acc_o[4][4];
    float l_part[4] = {0.f, 0.f, 0.f, 0.f};
    #pragma unroll
    for (int rg = 0; rg < 4; rg++)
        #pragma unroll
        for (int nt = 0; nt < 4; nt++)
            acc_o[rg][nt] = (floatx4){0.f, 0.f, 0.f, 0.f};
    const floatx4 zero4 = {0.f, 0.f, 0.f, 0.f};

    stage(0, 0);
    int buf = 0;
    for (int it = 0; it < niter; it++) {
        const int kb = it * 64;
        __syncthreads();
        if (it + 1 < niter) stage(buf ^ 1, kb + 64);

        short8 kf[4][2], vf[4][2];
        #pragma unroll
        for (int nt = 0; nt < 4; nt++)
            #pragma unroll
            for (int kk = 0; kk < 2; kk++) {
                kf[nt][kk] = *reinterpret_cast<const short8*>(
                    &Kt[buf][(nt * 16 + ln) * 64 + (((kk * 4 + quad) ^ (ln & 7)) << 3)]);
                vf[nt][kk] = *reinterpret_cast<const short8*>(
                    &Vt[buf][(nt * 16 + ln) * 64 + (((kk * 4 + quad) ^ (ln & 7)) << 3)]);
            }

        #pragma unroll
        for (int rg = 0; rg < 4; rg++) {
            if (kb <= rgbase[rg] + 15) {
                // S^T = K Q^T : lane holds S[q=ln][key = kb + nt*16 + quad*4 + r]
                floatx4 sacc[4];
                #pragma unroll
                for (int nt = 0; nt < 4; nt++) {
                    floatx4 s = __builtin_amdgcn_mfma_f32_16x16x32_bf16(kf[nt][0], qf[rg][0], zero4, 0, 0, 0);
                    sacc[nt] = __builtin_amdgcn_mfma_f32_16x16x32_bf16(kf[nt][1], qf[rg][1], s, 0, 0, 0);
                }
                const int qpos = rgbase[rg] + ln;
                if (kb + 63 > rgbase[rg]) {     // diagonal region: mask
                    #pragma unroll
                    for (int nt = 0; nt < 4; nt++) {
                        int kbase = kb + nt * 16 + quad * 4;
                        #pragma unroll
                        for (int r = 0; r < 4; r++)
                            if (kbase + r > qpos) sacc[nt][r] = -1e9f;
                    }
                }
                float lp = 0.f;
                #pragma unroll
                for (int nt = 0; nt < 4; nt++) {
                    #pragma unroll
                    for (int r = 0; r < 4; r++) {
                        float p = __expf(sacc[nt][r]);
                        sacc[nt][r] = p;
                        lp += p;
                    }
                }
                l_part[rg] += lp;
                // P[q=ln][key]: 4 contiguous bf16 per (nt) -> ds_write_b64
                #pragma unroll
                for (int nt = 0; nt < 4; nt++) {
                    short4v pk = { f2bf(sacc[nt][0]), f2bf(sacc[nt][1]),
                                   f2bf(sacc[nt][2]), f2bf(sacc[nt][3]) };
                    *reinterpret_cast<short4v*>(&P[w][ln * 72 + nt * 16 + quad * 4]) = pk;
                }
                short8 pa[2];
                #pragma unroll
                for (int kk = 0; kk < 2; kk++)
                    pa[kk] = *reinterpret_cast<const short8*>(&P[w][ln * 72 + kk * 32 + quad * 8]);
                #pragma unroll
                for (int nt = 0; nt < 4; nt++) {
                    floatx4 o = __builtin_amdgcn_mfma_f32_16x16x32_bf16(pa[0], vf[nt][0], acc_o[rg][nt], 0, 0, 0);
                    acc_o[rg][nt] = __builtin_amdgcn_mfma_f32_16x16x32_bf16(pa[1], vf[nt][1], o, 0, 0, 0);
                }
            }
        }
        buf ^= 1;
    }

    // Epilogue: l lives at lane ln for q=ln; redistribute to C/D rows via shfl.
    #pragma unroll
    for (int rg = 0; rg < 4; rg++) {
        float l = l_part[rg];
        l += __shfl_xor(l, 16, 64);
        l += __shfl_xor(l, 32, 64);
        #pragma unroll
        for (int r = 0; r < 4; r++) {
            float lv = __shfl(l, quad * 4 + r, 64);
            float rl = 1.f / lv;
            int row = rgbase[rg] + quad * 4 + r;
            #pragma unroll
            for (int nt = 0; nt < 4; nt++)
                o_ws[(size_t)row * DM + head * 64 + nt * 16 + ln] =
                    __float2bfloat16(acc_o[rg][nt][r] * rl);
        }
    }
}

// ---------------------------------------------------------------------------
// Kernel 3: O @ Wo^T -> fp32 out (unchanged from R7/R8 — verified).
// ---------------------------------------------------------------------------
__global__ __launch_bounds__(256) void oproj_kernel(
    const __hip_bfloat16* __restrict__ o_in,
    const float* __restrict__ Wo,
    float* __restrict__ out)
{
    __shared__ __align__(16) char smem[33792];
    short* As = (short*)smem;
    short* Bs = As + 8192;
    float* fpool = (float*)smem;

    const int m0 = blockIdx.x * 128;
    const int n0 = blockIdx.y * 128;

    const int t = threadIdx.x;
    const int lane = t & 63;
    const int w = t >> 6;
    const int quad = lane >> 4;
    const int ln = lane & 15;
    const int wm = (w >> 1) * 64;
    const int wn = (w & 1) * 64;

    floatx4 acc[4][4];
    #pragma unroll
    for (int i = 0; i < 4; i++)
        #pragma unroll
        for (int j = 0; j < 4; j++) acc[i][j] = (floatx4){0.f, 0.f, 0.f, 0.f};

    for (int k0 = 0; k0 < DM; k0 += 64) {
        #pragma unroll
        for (int it = 0; it < 4; it++) {
            int row = w * 32 + it * 8 + (lane >> 3);
            int sg = (lane & 7) ^ (row & 7);
            gl2lds16(&o_in[(size_t)(m0 + row) * DM + k0 + sg * 8], &As[(w * 32 + it * 8) * 64]);
        }
        #pragma unroll
        for (int p = 0; p < 4; p++) {
            int r = (t >> 3) + p * 32;
            int sg = t & 7;
            *reinterpret_cast<short8*>(&Bs[r * 64 + ((sg ^ (r & 7)) << 3)]) =
                load8_f32_as_bf16(&Wo[(size_t)(n0 + r) * DM + k0 + sg * 8]);
        }
        __syncthreads();

        short8 af[4][2], bfr[4][2];
        #pragma unroll
        for (int i = 0; i < 4; i++)
            #pragma unroll
            for (int kc = 0; kc < 2; kc++)
                af[i][kc] = *reinterpret_cast<const short8*>(
                    &As[(wm + i * 16 + ln) * 64 + (((kc * 4 + quad) ^ (ln & 7)) << 3)]);
        #pragma unroll
        for (int j = 0; j < 4; j++)
            #pragma unroll
            for (int kc = 0; kc < 2; kc++)
                bfr[j][kc] = *reinterpret_cast<const short8*>(
                    &Bs[(wn + j * 16 + ln) * 64 + (((kc * 4 + quad) ^ (ln & 7)) << 3)]);

        #pragma unroll
        for (int kc = 0; kc < 2; kc++)
            #pragma unroll
            for (int i = 0; i < 4; i++)
                #pragma unroll
                for (int j = 0; j < 4; j++)
                    acc[i][j] = __builtin_amdgcn_mfma_f32_16x16x32_bf16(
                        af[i][kc], bfr[j][kc], acc[i][j], 0, 0, 0);
        __syncthreads();
    }

    #pragma unroll
    for (int ph = 0; ph < 2; ph++) {
        if ((w >> 1) == ph) {
            #pragma unroll
            for (int j = 0; j < 4; j++)
                #pragma unroll
                for (int i = 0; i < 4; i++) {
                    int rl = i * 16 + quad * 4;
                    #pragma unroll
                    for (int r = 0; r < 4; r++)
                        fpool[(rl + r) * 132 + wn + j * 16 + ln] = acc[i][j][r];
                }
        }
        __syncthreads();
        int row = t >> 2;
        int c0 = (t & 3) * 32;
        size_t gbase = (size_t)(m0 + ph * 64 + row) * DM + n0 + c0;
        #pragma unroll
        for (int c = 0; c < 8; c++)
            *reinterpret_cast<float4*>(&out[gbase + c * 4]) =
                *reinterpret_cast<const float4*>(&fpool[row * 132 + c0 + c * 4]);
        __syncthreads();
    }
}

extern "C" void kernel_launch(void* const* d_in, const int* in_sizes, int n_in,
                              void* d_out, int out_size, void* d_ws, size_t ws_size,
                              hipStream_t stream) {
    const float* x  = (const float*)d_in[0];
    const int* tp   = (const int*)d_in[1];
    const float* Wq = (const float*)d_in[2];
    const float* Wk = (const float*)d_in[3];
    const float* Wv = (const float*)d_in[4];
    const float* Wo = (const float*)d_in[5];
    float* out = (float*)d_out;

    char* ws = (char*)d_ws;
    const size_t MB = 1024 * 1024;
    __hip_bfloat16* xb    = (__hip_bfloat16*)(ws);              // 8 MB; reused as o_ws
    __hip_bfloat16* q_ws  = (__hip_bfloat16*)(ws + 8  * MB);    // [SEQ][DM]
    __hip_bfloat16* k_ws  = (__hip_bfloat16*)(ws + 16 * MB);    // [SEQ][DM]
    __hip_bfloat16* vt_ws = (__hip_bfloat16*)(ws + 24 * MB);    // [1024][SEQ]
    __hip_bfloat16* o_ws  = xb;
    __hip_bfloat16* Wqb = (__hip_bfloat16*)d_out;                // parked in d_out
    __hip_bfloat16* Wkb = Wqb + (size_t)DM * DM;
    __hip_bfloat16* Wvb = Wkb + (size_t)DM * DM;
    float2* tab = (float2*)((char*)d_out + 6 * MB);

    prep_kernel<<<4096, 256, 0, stream>>>(x, Wq, Wk, Wv, tp, xb, Wqb, Wkb, Wvb, tab);
    qkv_rope_kernel<<<dim3(32, 24), 256, 0, stream>>>(xb, tab, Wqb, Wkb, Wvb, q_ws, k_ws, vt_ws);
    attn_kernel<<<dim3(16, 16), 256, 0, stream>>>(q_ws, k_ws, vt_ws, o_ws);
    oproj_kernel<<<dim3(32, 8), 256, 0, stream>>>(o_ws, Wo, out);
}

// Round 10
// 235.069 us; speedup vs baseline: 1.1234x; 1.1234x over previous
//
#include <hip/hip_runtime.h>
#include <hip/hip_bf16.h>
#include <math.h>

// CausalMHA+RoPE: B=1, S=4096, DM=1024, H=16, DK=64. fp32 in / fp32 out.
// R10 = R8 shape + R9 S^T math + conflict-free P layout.
// R9 post-mortem: 1 wave/SIMD (no latency hiding) + P b64 writes 4-way bank
// conflicts (3.2M). Now: 512 thr / 8 waves (2/SIMD), wave owns 16 rows of
// tile A=(31-bx) and 16 of tile B=bx (balanced, 66 tile-computes/block);
// S^T formulation (P writes = 4x ds_write_b64, row-sum scalar per lane);
// P pitch 64 + 8B-seg XOR swizzle e(ln)=((ln&7)<<1)^(ln&8) (even -> b128
// reads stay contiguous; 16 distinct e kill ln/ln+8 aliasing).

#define SEQ 4096
#define DM  1024
#define NH  16
#define DK  64

typedef __attribute__((ext_vector_type(8))) short short8;   // 8 bf16 (MFMA A/B frag)
typedef __attribute__((ext_vector_type(4))) float floatx4;  // MFMA C/D frag
typedef __attribute__((ext_vector_type(4))) short short4v;  // 4 bf16 (8 B)

static __device__ __forceinline__ short f2bf(float f) {
    __hip_bfloat16 h = __float2bfloat16(f);
    return __builtin_bit_cast(short, h);
}

static __device__ __forceinline__ short8 load8_f32_as_bf16(const float* p) {
    float4 a = *reinterpret_cast<const float4*>(p);
    float4 b = *reinterpret_cast<const float4*>(p + 4);
    short8 s;
    s[0] = f2bf(a.x); s[1] = f2bf(a.y); s[2] = f2bf(a.z); s[3] = f2bf(a.w);
    s[4] = f2bf(b.x); s[5] = f2bf(b.y); s[6] = f2bf(b.z); s[7] = f2bf(b.w);
    return s;
}

// async global->LDS, 16 B/lane. LDS dest = wave-uniform base + lane*16.
static __device__ __forceinline__ void gl2lds16(const __hip_bfloat16* g, short* l) {
    __builtin_amdgcn_global_load_lds(
        (const __attribute__((address_space(1))) unsigned int*)g,
        (__attribute__((address_space(3))) unsigned int*)l, 16, 0, 0);
}

static __device__ __forceinline__ int read_pos(const int* tp32, int s) {
    return (tp32[1] == 1) ? tp32[s] : tp32[2 * s];
}

// ---------------------------------------------------------------------------
// Fused prep: fp32->bf16 for x/Wq/Wk/Wv + RoPE cos/sin table. Grid 4096.
// ---------------------------------------------------------------------------
__global__ __launch_bounds__(256) void prep_kernel(
    const float* __restrict__ x,  const float* __restrict__ Wq,
    const float* __restrict__ Wk, const float* __restrict__ Wv,
    const int* __restrict__ tp,
    __hip_bfloat16* __restrict__ xb,  __hip_bfloat16* __restrict__ Wqb,
    __hip_bfloat16* __restrict__ Wkb, __hip_bfloat16* __restrict__ Wvb,
    float2* __restrict__ tab)
{
    int b = blockIdx.x;
    if (b < 3584) {
        const float* src; __hip_bfloat16* dst; int off;
        if (b < 2048)      { src = x;  dst = xb;  off = b; }
        else if (b < 2560) { src = Wq; dst = Wqb; off = b - 2048; }
        else if (b < 3072) { src = Wk; dst = Wkb; off = b - 2560; }
        else               { src = Wv; dst = Wvb; off = b - 3072; }
        size_t i = (size_t)off * 256 + threadIdx.x;
        short8 v = load8_f32_as_bf16(src + i * 8);
        *reinterpret_cast<short8*>((short*)dst + i * 8) = v;
    } else {
        int idx = (b - 3584) * 256 + threadIdx.x;   // SEQ*32 entries
        if (idx < SEQ * 32) {
            int s = idx >> 5, pair = idx & 31;
            float inv_freq = exp2f(-(float)(2 * pair) * (13.287712379549449f / 64.f));
            float sn, cs;
            sincosf((float)read_pos(tp, s) * inv_freq, &sn, &cs);
            tab[idx] = make_float2(cs, sn);
        }
    }
}

// ---------------------------------------------------------------------------
// Kernel 1: QKV NT-GEMM + RoPE epilogue (unchanged — verified R7/R8).
// ---------------------------------------------------------------------------
__global__ __launch_bounds__(256) void qkv_rope_kernel(
    const __hip_bfloat16* __restrict__ xb,
    const float2* __restrict__ tab,
    const __hip_bfloat16* __restrict__ Wqb,
    const __hip_bfloat16* __restrict__ Wkb,
    const __hip_bfloat16* __restrict__ Wvb,
    __hip_bfloat16* __restrict__ q_ws,
    __hip_bfloat16* __restrict__ k_ws,
    __hip_bfloat16* __restrict__ vt_ws)
{
    __shared__ __align__(16) short pool[17408];
    short* As = pool;
    short* Bs = pool + 8192;

    const int by = blockIdx.y;
    const int wsel = by >> 3;
    const __hip_bfloat16* W = (wsel == 0) ? Wqb : (wsel == 1 ? Wkb : Wvb);
    const int nloc0 = (by & 7) * 128;
    const int m0 = blockIdx.x * 128;

    const int t = threadIdx.x;
    const int lane = t & 63;
    const int w = t >> 6;
    const int quad = lane >> 4;
    const int ln = lane & 15;
    const int wm = (w >> 1) * 64;
    const int wn = (w & 1) * 64;

    floatx4 acc[4][4];
    #pragma unroll
    for (int i = 0; i < 4; i++)
        #pragma unroll
        for (int j = 0; j < 4; j++) acc[i][j] = (floatx4){0.f, 0.f, 0.f, 0.f};

    for (int k0 = 0; k0 < DM; k0 += 64) {
        #pragma unroll
        for (int it = 0; it < 4; it++) {
            int row = w * 32 + it * 8 + (lane >> 3);
            int sg = (lane & 7) ^ (row & 7);
            gl2lds16(&xb[(size_t)(m0 + row) * DM + k0 + sg * 8], &As[(w * 32 + it * 8) * 64]);
            gl2lds16(&W[(size_t)(nloc0 + row) * DM + k0 + sg * 8], &Bs[(w * 32 + it * 8) * 64]);
        }
        __syncthreads();

        short8 af[4][2], bfr[4][2];
        #pragma unroll
        for (int i = 0; i < 4; i++)
            #pragma unroll
            for (int kc = 0; kc < 2; kc++)
                af[i][kc] = *reinterpret_cast<const short8*>(
                    &As[(wm + i * 16 + ln) * 64 + (((kc * 4 + quad) ^ (ln & 7)) << 3)]);
        #pragma unroll
        for (int j = 0; j < 4; j++)
            #pragma unroll
            for (int kc = 0; kc < 2; kc++)
                bfr[j][kc] = *reinterpret_cast<const short8*>(
                    &Bs[(wn + j * 16 + ln) * 64 + (((kc * 4 + quad) ^ (ln & 7)) << 3)]);

        #pragma unroll
        for (int kc = 0; kc < 2; kc++)
            #pragma unroll
            for (int i = 0; i < 4; i++)
                #pragma unroll
                for (int j = 0; j < 4; j++)
                    acc[i][j] = __builtin_amdgcn_mfma_f32_16x16x32_bf16(
                        af[i][kc], bfr[j][kc], acc[i][j], 0, 0, 0);
        __syncthreads();
    }

    if (wsel < 2) {
        __hip_bfloat16* dst = (wsel == 0) ? q_ws : k_ws;
        const float qscale = (wsel == 0) ? 0.125f : 1.0f;
        #pragma unroll
        for (int j = 0; j < 4; j++) {
            int cnl = wn + j * 16 + ln;
            int pair = ((nloc0 + cnl) & 63) >> 1;
            #pragma unroll
            for (int i = 0; i < 4; i++) {
                int rowl = wm + i * 16 + quad * 4;
                #pragma unroll
                for (int r = 0; r < 4; r++) {
                    float2 t2 = tab[(size_t)(m0 + rowl + r) * 32 + pair];
                    float val = acc[i][j][r];
                    float partner = __shfl_xor(val, 1, 64);
                    float res = val * t2.x + (((lane & 1) ? partner : -partner) * t2.y);
                    pool[(rowl + r) * 136 + cnl] = f2bf(res * qscale);
                }
            }
        }
        __syncthreads();
        int row = t >> 1, half = t & 1;
        size_t gbase = (size_t)(m0 + row) * DM + nloc0 + half * 64;
        #pragma unroll
        for (int c = 0; c < 8; c++)
            *reinterpret_cast<short8*>(&dst[gbase + c * 8]) =
                *reinterpret_cast<const short8*>(&pool[row * 136 + half * 64 + c * 8]);
    } else {
        #pragma unroll
        for (int j = 0; j < 4; j++) {
            int cnl = wn + j * 16 + ln;
            #pragma unroll
            for (int i = 0; i < 4; i++) {
                int s0 = wm + i * 16 + quad * 4;
                #pragma unroll
                for (int r = 0; r < 4; r++)
                    pool[cnl * 136 + s0 + r] = f2bf(acc[i][j][r]);
            }
        }
        __syncthreads();
        int cnl = t >> 1, sh = t & 1;
        size_t base = (size_t)(nloc0 + cnl) * SEQ + m0 + sh * 64;
        #pragma unroll
        for (int c = 0; c < 8; c++)
            *reinterpret_cast<short8*>(&vt_ws[base + c * 8]) =
                *reinterpret_cast<const short8*>(&pool[cnl * 136 + sh * 64 + c * 8]);
    }
}

// ---------------------------------------------------------------------------
// Kernel 2: causal flash attention. Grid (16,16), 512 thr = 8 waves (2/SIMD).
// Wave owns 16 rows of tile A=(31-bx) and 16 of tile B=bx (66 computes/block).
// S^T: sacc = mfma(kf, qf) -> lane holds S[q=ln][key=kb+nt*16+quad*4+r].
// P: per-wave 16x64 bf16, pitch 64, seg-swizzle e(ln); write b64, read b128.
// ---------------------------------------------------------------------------
__global__ __launch_bounds__(512) void attn_kernel(
    const __hip_bfloat16* __restrict__ q_ws,
    const __hip_bfloat16* __restrict__ k_ws,
    const __hip_bfloat16* __restrict__ vt_ws,
    __hip_bfloat16* __restrict__ o_ws)   // [SEQ][DM]
{
    __shared__ __align__(16) short Kt[2][64 * 64];
    __shared__ __align__(16) short Vt[2][64 * 64];
    __shared__ __align__(16) short P[8][16 * 64];   // pitch 64, swizzled

    const int head = blockIdx.y;
    const int bx = blockIdx.x;            // 0..15
    const int qbA0 = (31 - bx) * 128;     // long tile
    const int qbB0 = bx * 128;            // short tile
    const int t = threadIdx.x;
    const int lane = t & 63;
    const int w = t >> 6;                 // 0..7
    const int quad = lane >> 4;
    const int ln = lane & 15;
    const int niter = (31 - bx) * 2 + 2;

    const int qAbase = qbA0 + w * 16;
    const int qBbase = qbB0 + w * 16;
    const int e = ((ln & 7) << 1) ^ (ln & 8);   // P seg swizzle (even, 16 distinct)

    const int keyl = w * 8 + (lane >> 3); // row of the 64-tile this lane stages
    const int sg = (lane & 7) ^ (keyl & 7);

    auto stage = [&](int b, int kb) {
        gl2lds16(&k_ws[(size_t)(kb + keyl) * DM + head * 64 + sg * 8], &Kt[b][w * 512]);
        gl2lds16(&vt_ws[(size_t)(head * 64 + keyl) * SEQ + kb + sg * 8], &Vt[b][w * 512]);
    };

    short8 qfA[2], qfB[2];
    #pragma unroll
    for (int kk = 0; kk < 2; kk++) {
        qfA[kk] = *reinterpret_cast<const short8*>(
            &q_ws[(size_t)(qAbase + ln) * DM + head * 64 + kk * 32 + quad * 8]);
        qfB[kk] = *reinterpret_cast<const short8*>(
            &q_ws[(size_t)(qBbase + ln) * DM + head * 64 + kk * 32 + quad * 8]);
    }

    floatx4 accA[4], accB[4];
    float lA = 0.f, lB = 0.f;             // per-lane scalar: q = ln (S^T)
    #pragma unroll
    for (int nt = 0; nt < 4; nt++) {
        accA[nt] = (floatx4){0.f, 0.f, 0.f, 0.f};
        accB[nt] = (floatx4){0.f, 0.f, 0.f, 0.f};
    }
    const floatx4 zero4 = {0.f, 0.f, 0.f, 0.f};

    stage(0, 0);
    int buf = 0;
    for (int it = 0; it < niter; it++) {
        const int kb = it * 64;
        __syncthreads();
        if (it + 1 < niter) stage(buf ^ 1, kb + 64);

        short8 kf[4][2], vf[4][2];
        #pragma unroll
        for (int nt = 0; nt < 4; nt++)
            #pragma unroll
            for (int kk = 0; kk < 2; kk++) {
                kf[nt][kk] = *reinterpret_cast<const short8*>(
                    &Kt[buf][(nt * 16 + ln) * 64 + (((kk * 4 + quad) ^ (ln & 7)) << 3)]);
                vf[nt][kk] = *reinterpret_cast<const short8*>(
                    &Vt[buf][(nt * 16 + ln) * 64 + (((kk * 4 + quad) ^ (ln & 7)) << 3)]);
            }

        // ---------------- tile A -------------------------------------------
        if (kb <= qAbase + 15) {
            floatx4 sacc[4];
            #pragma unroll
            for (int nt = 0; nt < 4; nt++) {
                floatx4 s = __builtin_amdgcn_mfma_f32_16x16x32_bf16(kf[nt][0], qfA[0], zero4, 0, 0, 0);
                sacc[nt] = __builtin_amdgcn_mfma_f32_16x16x32_bf16(kf[nt][1], qfA[1], s, 0, 0, 0);
            }
            const int qpos = qAbase + ln;
            if (kb + 63 > qAbase) {
                #pragma unroll
                for (int nt = 0; nt < 4; nt++) {
                    int kbase = kb + nt * 16 + quad * 4;
                    #pragma unroll
                    for (int r = 0; r < 4; r++)
                        if (kbase + r > qpos) sacc[nt][r] = -1e9f;
                }
            }
            #pragma unroll
            for (int nt = 0; nt < 4; nt++)
                #pragma unroll
                for (int r = 0; r < 4; r++) {
                    float p = __expf(sacc[nt][r]);
                    sacc[nt][r] = p;
                    lA += p;
                }
            #pragma unroll
            for (int nt = 0; nt < 4; nt++) {
                short4v pk = { f2bf(sacc[nt][0]), f2bf(sacc[nt][1]),
                               f2bf(sacc[nt][2]), f2bf(sacc[nt][3]) };
                *reinterpret_cast<short4v*>(&P[w][ln * 64 + (((nt * 4 + quad) ^ e) << 2)]) = pk;
            }
            short8 pa[2];
            #pragma unroll
            for (int kk = 0; kk < 2; kk++)
                pa[kk] = *reinterpret_cast<const short8*>(
                    &P[w][ln * 64 + (((kk * 8 + quad * 2) ^ e) << 2)]);
            #pragma unroll
            for (int nt = 0; nt < 4; nt++) {
                floatx4 o = __builtin_amdgcn_mfma_f32_16x16x32_bf16(pa[0], vf[nt][0], accA[nt], 0, 0, 0);
                accA[nt] = __builtin_amdgcn_mfma_f32_16x16x32_bf16(pa[1], vf[nt][1], o, 0, 0, 0);
            }
        }
        // ---------------- tile B (early iters only) ------------------------
        if (kb <= qBbase + 15) {
            floatx4 sacc[4];
            #pragma unroll
            for (int nt = 0; nt < 4; nt++) {
                floatx4 s = __builtin_amdgcn_mfma_f32_16x16x32_bf16(kf[nt][0], qfB[0], zero4, 0, 0, 0);
                sacc[nt] = __builtin_amdgcn_mfma_f32_16x16x32_bf16(kf[nt][1], qfB[1], s, 0, 0, 0);
            }
            const int qpos = qBbase + ln;
            if (kb + 63 > qBbase) {
                #pragma unroll
                for (int nt = 0; nt < 4; nt++) {
                    int kbase = kb + nt * 16 + quad * 4;
                    #pragma unroll
                    for (int r = 0; r < 4; r++)
                        if (kbase + r > qpos) sacc[nt][r] = -1e9f;
                }
            }
            #pragma unroll
            for (int nt = 0; nt < 4; nt++)
                #pragma unroll
                for (int r = 0; r < 4; r++) {
                    float p = __expf(sacc[nt][r]);
                    sacc[nt][r] = p;
                    lB += p;
                }
            // P[w] reuse after A's reads: same-wave LDS ops are in-order
            #pragma unroll
            for (int nt = 0; nt < 4; nt++) {
                short4v pk = { f2bf(sacc[nt][0]), f2bf(sacc[nt][1]),
                               f2bf(sacc[nt][2]), f2bf(sacc[nt][3]) };
                *reinterpret_cast<short4v*>(&P[w][ln * 64 + (((nt * 4 + quad) ^ e) << 2)]) = pk;
            }
            short8 pa[2];
            #pragma unroll
            for (int kk = 0; kk < 2; kk++)
                pa[kk] = *reinterpret_cast<const short8*>(
                    &P[w][ln * 64 + (((kk * 8 + quad * 2) ^ e) << 2)]);
            #pragma unroll
            for (int nt = 0; nt < 4; nt++) {
                floatx4 o = __builtin_amdgcn_mfma_f32_16x16x32_bf16(pa[0], vf[nt][0], accB[nt], 0, 0, 0);
                accB[nt] = __builtin_amdgcn_mfma_f32_16x16x32_bf16(pa[1], vf[nt][1], o, 0, 0, 0);
            }
        }
        buf ^= 1;
    }

    // Epilogue. l lives at lane with ln == q; reduce over quads, shfl to rows.
    {
        float l = lA;
        l += __shfl_xor(l, 16, 64);
        l += __shfl_xor(l, 32, 64);
        #pragma unroll
        for (int r = 0; r < 4; r++) {
            float rl = 1.f / __shfl(l, quad * 4 + r, 64);
            int row = qAbase + quad * 4 + r;
            #pragma unroll
            for (int nt = 0; nt < 4; nt++)
                o_ws[(size_t)row * DM + head * 64 + nt * 16 + ln] =
                    __float2bfloat16(accA[nt][r] * rl);
        }
    }
    {
        float l = lB;
        l += __shfl_xor(l, 16, 64);
        l += __shfl_xor(l, 32, 64);
        #pragma unroll
        for (int r = 0; r < 4; r++) {
            float rl = 1.f / __shfl(l, quad * 4 + r, 64);
            int row = qBbase + quad * 4 + r;
            #pragma unroll
            for (int nt = 0; nt < 4; nt++)
                o_ws[(size_t)row * DM + head * 64 + nt * 16 + ln] =
                    __float2bfloat16(accB[nt][r] * rl);
        }
    }
}

// ---------------------------------------------------------------------------
// Kernel 3: O @ Wo^T -> fp32 out (unchanged — verified R7/R8).
// ---------------------------------------------------------------------------
__global__ __launch_bounds__(256) void oproj_kernel(
    const __hip_bfloat16* __restrict__ o_in,
    const float* __restrict__ Wo,
    float* __restrict__ out)
{
    __shared__ __align__(16) char smem[33792];
    short* As = (short*)smem;
    short* Bs = As + 8192;
    float* fpool = (float*)smem;

    const int m0 = blockIdx.x * 128;
    const int n0 = blockIdx.y * 128;

    const int t = threadIdx.x;
    const int lane = t & 63;
    const int w = t >> 6;
    const int quad = lane >> 4;
    const int ln = lane & 15;
    const int wm = (w >> 1) * 64;
    const int wn = (w & 1) * 64;

    floatx4 acc[4][4];
    #pragma unroll
    for (int i = 0; i < 4; i++)
        #pragma unroll
        for (int j = 0; j < 4; j++) acc[i][j] = (floatx4){0.f, 0.f, 0.f, 0.f};

    for (int k0 = 0; k0 < DM; k0 += 64) {
        #pragma unroll
        for (int it = 0; it < 4; it++) {
            int row = w * 32 + it * 8 + (lane >> 3);
            int sg = (lane & 7) ^ (row & 7);
            gl2lds16(&o_in[(size_t)(m0 + row) * DM + k0 + sg * 8], &As[(w * 32 + it * 8) * 64]);
        }
        #pragma unroll
        for (int p = 0; p < 4; p++) {
            int r = (t >> 3) + p * 32;
            int sg2 = t & 7;
            *reinterpret_cast<short8*>(&Bs[r * 64 + ((sg2 ^ (r & 7)) << 3)]) =
                load8_f32_as_bf16(&Wo[(size_t)(n0 + r) * DM + k0 + sg2 * 8]);
        }
        __syncthreads();

        short8 af[4][2], bfr[4][2];
        #pragma unroll
        for (int i = 0; i < 4; i++)
            #pragma unroll
            for (int kc = 0; kc < 2; kc++)
                af[i][kc] = *reinterpret_cast<const short8*>(
                    &As[(wm + i * 16 + ln) * 64 + (((kc * 4 + quad) ^ (ln & 7)) << 3)]);
        #pragma unroll
        for (int j = 0; j < 4; j++)
            #pragma unroll
            for (int kc = 0; kc < 2; kc++)
                bfr[j][kc] = *reinterpret_cast<const short8*>(
                    &Bs[(wn + j * 16 + ln) * 64 + (((kc * 4 + quad) ^ (ln & 7)) << 3)]);

        #pragma unroll
        for (int kc = 0; kc < 2; kc++)
            #pragma unroll
            for (int i = 0; i < 4; i++)
                #pragma unroll
                for (int j = 0; j < 4; j++)
                    acc[i][j] = __builtin_amdgcn_mfma_f32_16x16x32_bf16(
                        af[i][kc], bfr[j][kc], acc[i][j], 0, 0, 0);
        __syncthreads();
    }

    #pragma unroll
    for (int ph = 0; ph < 2; ph++) {
        if ((w >> 1) == ph) {
            #pragma unroll
            for (int j = 0; j < 4; j++)
                #pragma unroll
                for (int i = 0; i < 4; i++) {
                    int rl = i * 16 + quad * 4;
                    #pragma unroll
                    for (int r = 0; r < 4; r++)
                        fpool[(rl + r) * 132 + wn + j * 16 + ln] = acc[i][j][r];
                }
        }
        __syncthreads();
        int row = t >> 2;
        int c0 = (t & 3) * 32;
        size_t gbase = (size_t)(m0 + ph * 64 + row) * DM + n0 + c0;
        #pragma unroll
        for (int c = 0; c < 8; c++)
            *reinterpret_cast<float4*>(&out[gbase + c * 4]) =
                *reinterpret_cast<const float4*>(&fpool[row * 132 + c0 + c * 4]);
        __syncthreads();
    }
}

extern "C" void kernel_launch(void* const* d_in, const int* in_sizes, int n_in,
                              void* d_out, int out_size, void* d_ws, size_t ws_size,
                              hipStream_t stream) {
    const float* x  = (const float*)d_in[0];
    const int* tp   = (const int*)d_in[1];
    const float* Wq = (const float*)d_in[2];
    const float* Wk = (const float*)d_in[3];
    const float* Wv = (const float*)d_in[4];
    const float* Wo = (const float*)d_in[5];
    float* out = (float*)d_out;

    char* ws = (char*)d_ws;
    const size_t MB = 1024 * 1024;
    __hip_bfloat16* xb    = (__hip_bfloat16*)(ws);              // 8 MB; reused as o_ws
    __hip_bfloat16* q_ws  = (__hip_bfloat16*)(ws + 8  * MB);    // [SEQ][DM]
    __hip_bfloat16* k_ws  = (__hip_bfloat16*)(ws + 16 * MB);    // [SEQ][DM]
    __hip_bfloat16* vt_ws = (__hip_bfloat16*)(ws + 24 * MB);    // [1024][SEQ]
    __hip_bfloat16* o_ws  = xb;
    __hip_bfloat16* Wqb = (__hip_bfloat16*)d_out;                // parked in d_out
    __hip_bfloat16* Wkb = Wqb + (size_t)DM * DM;
    __hip_bfloat16* Wvb = Wkb + (size_t)DM * DM;
    float2* tab = (float2*)((char*)d_out + 6 * MB);

    prep_kernel<<<4096, 256, 0, stream>>>(x, Wq, Wk, Wv, tp, xb, Wqb, Wkb, Wvb, tab);
    qkv_rope_kernel<<<dim3(32, 24), 256, 0, stream>>>(xb, tab, Wqb, Wkb, Wvb, q_ws, k_ws, vt_ws);
    attn_kernel<<<dim3(16, 16), 512, 0, stream>>>(q_ws, k_ws, vt_ws, o_ws);
    oproj_kernel<<<dim3(32, 8), 256, 0, stream>>>(o_ws, Wo, out);
}

// Round 11
// 220.690 us; speedup vs baseline: 1.1966x; 1.0652x over previous
//
#include <hip/hip_runtime.h>
#include <hip/hip_bf16.h>
#include <math.h>

// CausalMHA+RoPE: B=1, S=4096, DM=1024, H=16, DK=64. fp32 in / fp32 out.
// R11: (1) oproj 128x64 tiles grid (32,16) -> 2 blocks/CU, 2 waves/SIMD (was
//      1 wave/SIMD, R9-style exposed latency); (2) attn stages 128 keys per
//      barrier (2 sub-tiles/buffer, 33 barriers instead of 66, 2x prefetch
//      distance). All verified math/layouts unchanged.

#define SEQ 4096
#define DM  1024
#define NH  16
#define DK  64

typedef __attribute__((ext_vector_type(8))) short short8;   // 8 bf16 (MFMA A/B frag)
typedef __attribute__((ext_vector_type(4))) float floatx4;  // MFMA C/D frag
typedef __attribute__((ext_vector_type(4))) short short4v;  // 4 bf16 (8 B)

static __device__ __forceinline__ short f2bf(float f) {
    __hip_bfloat16 h = __float2bfloat16(f);
    return __builtin_bit_cast(short, h);
}

static __device__ __forceinline__ short8 load8_f32_as_bf16(const float* p) {
    float4 a = *reinterpret_cast<const float4*>(p);
    float4 b = *reinterpret_cast<const float4*>(p + 4);
    short8 s;
    s[0] = f2bf(a.x); s[1] = f2bf(a.y); s[2] = f2bf(a.z); s[3] = f2bf(a.w);
    s[4] = f2bf(b.x); s[5] = f2bf(b.y); s[6] = f2bf(b.z); s[7] = f2bf(b.w);
    return s;
}

// async global->LDS, 16 B/lane. LDS dest = wave-uniform base + lane*16.
static __device__ __forceinline__ void gl2lds16(const __hip_bfloat16* g, short* l) {
    __builtin_amdgcn_global_load_lds(
        (const __attribute__((address_space(1))) unsigned int*)g,
        (__attribute__((address_space(3))) unsigned int*)l, 16, 0, 0);
}

static __device__ __forceinline__ int read_pos(const int* tp32, int s) {
    return (tp32[1] == 1) ? tp32[s] : tp32[2 * s];
}

// ---------------------------------------------------------------------------
// Fused prep: fp32->bf16 for x/Wq/Wk/Wv + RoPE cos/sin table. Grid 4096.
// ---------------------------------------------------------------------------
__global__ __launch_bounds__(256) void prep_kernel(
    const float* __restrict__ x,  const float* __restrict__ Wq,
    const float* __restrict__ Wk, const float* __restrict__ Wv,
    const int* __restrict__ tp,
    __hip_bfloat16* __restrict__ xb,  __hip_bfloat16* __restrict__ Wqb,
    __hip_bfloat16* __restrict__ Wkb, __hip_bfloat16* __restrict__ Wvb,
    float2* __restrict__ tab)
{
    int b = blockIdx.x;
    if (b < 3584) {
        const float* src; __hip_bfloat16* dst; int off;
        if (b < 2048)      { src = x;  dst = xb;  off = b; }
        else if (b < 2560) { src = Wq; dst = Wqb; off = b - 2048; }
        else if (b < 3072) { src = Wk; dst = Wkb; off = b - 2560; }
        else               { src = Wv; dst = Wvb; off = b - 3072; }
        size_t i = (size_t)off * 256 + threadIdx.x;
        short8 v = load8_f32_as_bf16(src + i * 8);
        *reinterpret_cast<short8*>((short*)dst + i * 8) = v;
    } else {
        int idx = (b - 3584) * 256 + threadIdx.x;   // SEQ*32 entries
        if (idx < SEQ * 32) {
            int s = idx >> 5, pair = idx & 31;
            float inv_freq = exp2f(-(float)(2 * pair) * (13.287712379549449f / 64.f));
            float sn, cs;
            sincosf((float)read_pos(tp, s) * inv_freq, &sn, &cs);
            tab[idx] = make_float2(cs, sn);
        }
    }
}

// ---------------------------------------------------------------------------
// Kernel 1: QKV NT-GEMM + RoPE epilogue (unchanged — verified R7-R10).
// ---------------------------------------------------------------------------
__global__ __launch_bounds__(256) void qkv_rope_kernel(
    const __hip_bfloat16* __restrict__ xb,
    const float2* __restrict__ tab,
    const __hip_bfloat16* __restrict__ Wqb,
    const __hip_bfloat16* __restrict__ Wkb,
    const __hip_bfloat16* __restrict__ Wvb,
    __hip_bfloat16* __restrict__ q_ws,
    __hip_bfloat16* __restrict__ k_ws,
    __hip_bfloat16* __restrict__ vt_ws)
{
    __shared__ __align__(16) short pool[17408];
    short* As = pool;
    short* Bs = pool + 8192;

    const int by = blockIdx.y;
    const int wsel = by >> 3;
    const __hip_bfloat16* W = (wsel == 0) ? Wqb : (wsel == 1 ? Wkb : Wvb);
    const int nloc0 = (by & 7) * 128;
    const int m0 = blockIdx.x * 128;

    const int t = threadIdx.x;
    const int lane = t & 63;
    const int w = t >> 6;
    const int quad = lane >> 4;
    const int ln = lane & 15;
    const int wm = (w >> 1) * 64;
    const int wn = (w & 1) * 64;

    floatx4 acc[4][4];
    #pragma unroll
    for (int i = 0; i < 4; i++)
        #pragma unroll
        for (int j = 0; j < 4; j++) acc[i][j] = (floatx4){0.f, 0.f, 0.f, 0.f};

    for (int k0 = 0; k0 < DM; k0 += 64) {
        #pragma unroll
        for (int it = 0; it < 4; it++) {
            int row = w * 32 + it * 8 + (lane >> 3);
            int sg = (lane & 7) ^ (row & 7);
            gl2lds16(&xb[(size_t)(m0 + row) * DM + k0 + sg * 8], &As[(w * 32 + it * 8) * 64]);
            gl2lds16(&W[(size_t)(nloc0 + row) * DM + k0 + sg * 8], &Bs[(w * 32 + it * 8) * 64]);
        }
        __syncthreads();

        short8 af[4][2], bfr[4][2];
        #pragma unroll
        for (int i = 0; i < 4; i++)
            #pragma unroll
            for (int kc = 0; kc < 2; kc++)
                af[i][kc] = *reinterpret_cast<const short8*>(
                    &As[(wm + i * 16 + ln) * 64 + (((kc * 4 + quad) ^ (ln & 7)) << 3)]);
        #pragma unroll
        for (int j = 0; j < 4; j++)
            #pragma unroll
            for (int kc = 0; kc < 2; kc++)
                bfr[j][kc] = *reinterpret_cast<const short8*>(
                    &Bs[(wn + j * 16 + ln) * 64 + (((kc * 4 + quad) ^ (ln & 7)) << 3)]);

        #pragma unroll
        for (int kc = 0; kc < 2; kc++)
            #pragma unroll
            for (int i = 0; i < 4; i++)
                #pragma unroll
                for (int j = 0; j < 4; j++)
                    acc[i][j] = __builtin_amdgcn_mfma_f32_16x16x32_bf16(
                        af[i][kc], bfr[j][kc], acc[i][j], 0, 0, 0);
        __syncthreads();
    }

    if (wsel < 2) {
        __hip_bfloat16* dst = (wsel == 0) ? q_ws : k_ws;
        const float qscale = (wsel == 0) ? 0.125f : 1.0f;
        #pragma unroll
        for (int j = 0; j < 4; j++) {
            int cnl = wn + j * 16 + ln;
            int pair = ((nloc0 + cnl) & 63) >> 1;
            #pragma unroll
            for (int i = 0; i < 4; i++) {
                int rowl = wm + i * 16 + quad * 4;
                #pragma unroll
                for (int r = 0; r < 4; r++) {
                    float2 t2 = tab[(size_t)(m0 + rowl + r) * 32 + pair];
                    float val = acc[i][j][r];
                    float partner = __shfl_xor(val, 1, 64);
                    float res = val * t2.x + (((lane & 1) ? partner : -partner) * t2.y);
                    pool[(rowl + r) * 136 + cnl] = f2bf(res * qscale);
                }
            }
        }
        __syncthreads();
        int row = t >> 1, half = t & 1;
        size_t gbase = (size_t)(m0 + row) * DM + nloc0 + half * 64;
        #pragma unroll
        for (int c = 0; c < 8; c++)
            *reinterpret_cast<short8*>(&dst[gbase + c * 8]) =
                *reinterpret_cast<const short8*>(&pool[row * 136 + half * 64 + c * 8]);
    } else {
        #pragma unroll
        for (int j = 0; j < 4; j++) {
            int cnl = wn + j * 16 + ln;
            #pragma unroll
            for (int i = 0; i < 4; i++) {
                int s0 = wm + i * 16 + quad * 4;
                #pragma unroll
                for (int r = 0; r < 4; r++)
                    pool[cnl * 136 + s0 + r] = f2bf(acc[i][j][r]);
            }
        }
        __syncthreads();
        int cnl = t >> 1, sh = t & 1;
        size_t base = (size_t)(nloc0 + cnl) * SEQ + m0 + sh * 64;
        #pragma unroll
        for (int c = 0; c < 8; c++)
            *reinterpret_cast<short8*>(&vt_ws[base + c * 8]) =
                *reinterpret_cast<const short8*>(&pool[cnl * 136 + sh * 64 + c * 8]);
    }
}

// ---------------------------------------------------------------------------
// Kernel 2: causal flash attention. Grid (16,16), 512 thr = 8 waves (2/SIMD).
// Wave: 16 rows of tile A=(31-bx) + 16 of tile B=bx. S^T math (R10, verified).
// R11: 128 keys staged per barrier (2 x 64-key sub-tiles per buffer).
// ---------------------------------------------------------------------------
__global__ __launch_bounds__(512) void attn_kernel(
    const __hip_bfloat16* __restrict__ q_ws,
    const __hip_bfloat16* __restrict__ k_ws,
    const __hip_bfloat16* __restrict__ vt_ws,
    __hip_bfloat16* __restrict__ o_ws)   // [SEQ][DM]
{
    __shared__ __align__(16) short Kt[2][2][64 * 64];   // [buf][half]
    __shared__ __align__(16) short Vt[2][2][64 * 64];
    __shared__ __align__(16) short P[8][16 * 64];       // pitch 64, swizzled

    const int head = blockIdx.y;
    const int bx = blockIdx.x;            // 0..15
    const int qbA0 = (31 - bx) * 128;     // long tile
    const int qbB0 = bx * 128;            // short tile
    const int t = threadIdx.x;
    const int lane = t & 63;
    const int w = t >> 6;                 // 0..7
    const int quad = lane >> 4;
    const int ln = lane & 15;
    const int nstep = (31 - bx) + 1;      // 128-key steps; covers keys <= qbA0+127

    const int qAbase = qbA0 + w * 16;
    const int qBbase = qbB0 + w * 16;
    const int e = ((ln & 7) << 1) ^ (ln & 8);   // P seg swizzle

    const int keyl = w * 8 + (lane >> 3); // row of a 64-tile this lane stages
    const int sg = (lane & 7) ^ (keyl & 7);

    auto stage = [&](int b, int kb) {     // stages keys [kb, kb+128)
        #pragma unroll
        for (int h = 0; h < 2; h++) {
            gl2lds16(&k_ws[(size_t)(kb + h * 64 + keyl) * DM + head * 64 + sg * 8],
                     &Kt[b][h][w * 512]);
            gl2lds16(&vt_ws[(size_t)(head * 64 + keyl) * SEQ + kb + h * 64 + sg * 8],
                     &Vt[b][h][w * 512]);
        }
    };

    short8 qfA[2], qfB[2];
    #pragma unroll
    for (int kk = 0; kk < 2; kk++) {
        qfA[kk] = *reinterpret_cast<const short8*>(
            &q_ws[(size_t)(qAbase + ln) * DM + head * 64 + kk * 32 + quad * 8]);
        qfB[kk] = *reinterpret_cast<const short8*>(
            &q_ws[(size_t)(qBbase + ln) * DM + head * 64 + kk * 32 + quad * 8]);
    }

    floatx4 accA[4], accB[4];
    float lA = 0.f, lB = 0.f;             // per-lane scalar: q = ln (S^T)
    #pragma unroll
    for (int nt = 0; nt < 4; nt++) {
        accA[nt] = (floatx4){0.f, 0.f, 0.f, 0.f};
        accB[nt] = (floatx4){0.f, 0.f, 0.f, 0.f};
    }
    const floatx4 zero4 = {0.f, 0.f, 0.f, 0.f};

    stage(0, 0);
    int buf = 0;
    for (int st = 0; st < nstep; st++) {
        __syncthreads();
        if (st + 1 < nstep) stage(buf ^ 1, (st + 1) * 128);

        #pragma unroll
        for (int h = 0; h < 2; h++) {
            const int kb = st * 128 + h * 64;
            if (kb > qAbase + 15 && kb > qBbase + 15) continue;

            short8 kf[4][2], vf[4][2];
            #pragma unroll
            for (int nt = 0; nt < 4; nt++)
                #pragma unroll
                for (int kk = 0; kk < 2; kk++) {
                    kf[nt][kk] = *reinterpret_cast<const short8*>(
                        &Kt[buf][h][(nt * 16 + ln) * 64 + (((kk * 4 + quad) ^ (ln & 7)) << 3)]);
                    vf[nt][kk] = *reinterpret_cast<const short8*>(
                        &Vt[buf][h][(nt * 16 + ln) * 64 + (((kk * 4 + quad) ^ (ln & 7)) << 3)]);
                }

            // ---------------- tile A ---------------------------------------
            if (kb <= qAbase + 15) {
                floatx4 sacc[4];
                #pragma unroll
                for (int nt = 0; nt < 4; nt++) {
                    floatx4 s = __builtin_amdgcn_mfma_f32_16x16x32_bf16(kf[nt][0], qfA[0], zero4, 0, 0, 0);
                    sacc[nt] = __builtin_amdgcn_mfma_f32_16x16x32_bf16(kf[nt][1], qfA[1], s, 0, 0, 0);
                }
                const int qpos = qAbase + ln;
                if (kb + 63 > qAbase) {
                    #pragma unroll
                    for (int nt = 0; nt < 4; nt++) {
                        int kbase = kb + nt * 16 + quad * 4;
                        #pragma unroll
                        for (int r = 0; r < 4; r++)
                            if (kbase + r > qpos) sacc[nt][r] = -1e9f;
                    }
                }
                #pragma unroll
                for (int nt = 0; nt < 4; nt++)
                    #pragma unroll
                    for (int r = 0; r < 4; r++) {
                        float p = __expf(sacc[nt][r]);
                        sacc[nt][r] = p;
                        lA += p;
                    }
                #pragma unroll
                for (int nt = 0; nt < 4; nt++) {
                    short4v pk = { f2bf(sacc[nt][0]), f2bf(sacc[nt][1]),
                                   f2bf(sacc[nt][2]), f2bf(sacc[nt][3]) };
                    *reinterpret_cast<short4v*>(&P[w][ln * 64 + (((nt * 4 + quad) ^ e) << 2)]) = pk;
                }
                short8 pa[2];
                #pragma unroll
                for (int kk = 0; kk < 2; kk++)
                    pa[kk] = *reinterpret_cast<const short8*>(
                        &P[w][ln * 64 + (((kk * 8 + quad * 2) ^ e) << 2)]);
                #pragma unroll
                for (int nt = 0; nt < 4; nt++) {
                    floatx4 o = __builtin_amdgcn_mfma_f32_16x16x32_bf16(pa[0], vf[nt][0], accA[nt], 0, 0, 0);
                    accA[nt] = __builtin_amdgcn_mfma_f32_16x16x32_bf16(pa[1], vf[nt][1], o, 0, 0, 0);
                }
            }
            // ---------------- tile B (early steps only) --------------------
            if (kb <= qBbase + 15) {
                floatx4 sacc[4];
                #pragma unroll
                for (int nt = 0; nt < 4; nt++) {
                    floatx4 s = __builtin_amdgcn_mfma_f32_16x16x32_bf16(kf[nt][0], qfB[0], zero4, 0, 0, 0);
                    sacc[nt] = __builtin_amdgcn_mfma_f32_16x16x32_bf16(kf[nt][1], qfB[1], s, 0, 0, 0);
                }
                const int qpos = qBbase + ln;
                if (kb + 63 > qBbase) {
                    #pragma unroll
                    for (int nt = 0; nt < 4; nt++) {
                        int kbase = kb + nt * 16 + quad * 4;
                        #pragma unroll
                        for (int r = 0; r < 4; r++)
                            if (kbase + r > qpos) sacc[nt][r] = -1e9f;
                    }
                }
                #pragma unroll
                for (int nt = 0; nt < 4; nt++)
                    #pragma unroll
                    for (int r = 0; r < 4; r++) {
                        float p = __expf(sacc[nt][r]);
                        sacc[nt][r] = p;
                        lB += p;
                    }
                // P[w] reuse after A's reads: same-wave LDS ops are in-order
                #pragma unroll
                for (int nt = 0; nt < 4; nt++) {
                    short4v pk = { f2bf(sacc[nt][0]), f2bf(sacc[nt][1]),
                                   f2bf(sacc[nt][2]), f2bf(sacc[nt][3]) };
                    *reinterpret_cast<short4v*>(&P[w][ln * 64 + (((nt * 4 + quad) ^ e) << 2)]) = pk;
                }
                short8 pa[2];
                #pragma unroll
                for (int kk = 0; kk < 2; kk++)
                    pa[kk] = *reinterpret_cast<const short8*>(
                        &P[w][ln * 64 + (((kk * 8 + quad * 2) ^ e) << 2)]);
                #pragma unroll
                for (int nt = 0; nt < 4; nt++) {
                    floatx4 o = __builtin_amdgcn_mfma_f32_16x16x32_bf16(pa[0], vf[nt][0], accB[nt], 0, 0, 0);
                    accB[nt] = __builtin_amdgcn_mfma_f32_16x16x32_bf16(pa[1], vf[nt][1], o, 0, 0, 0);
                }
            }
        }
        buf ^= 1;
    }

    // Epilogue. l lives at lane with ln == q; reduce over quads, shfl to rows.
    {
        float l = lA;
        l += __shfl_xor(l, 16, 64);
        l += __shfl_xor(l, 32, 64);
        #pragma unroll
        for (int r = 0; r < 4; r++) {
            float rl = 1.f / __shfl(l, quad * 4 + r, 64);
            int row = qAbase + quad * 4 + r;
            #pragma unroll
            for (int nt = 0; nt < 4; nt++)
                o_ws[(size_t)row * DM + head * 64 + nt * 16 + ln] =
                    __float2bfloat16(accA[nt][r] * rl);
        }
    }
    {
        float l = lB;
        l += __shfl_xor(l, 16, 64);
        l += __shfl_xor(l, 32, 64);
        #pragma unroll
        for (int r = 0; r < 4; r++) {
            float rl = 1.f / __shfl(l, quad * 4 + r, 64);
            int row = qBbase + quad * 4 + r;
            #pragma unroll
            for (int nt = 0; nt < 4; nt++)
                o_ws[(size_t)row * DM + head * 64 + nt * 16 + ln] =
                    __float2bfloat16(accB[nt][r] * rl);
        }
    }
}

// ---------------------------------------------------------------------------
// Kernel 3: O @ Wo^T -> fp32 out. R11: 128x64 tiles, grid (32,16) = 512 blocks
// = 2 blocks/CU = 2 waves/SIMD (latency hiding). Wave = 64x32 out.
// ---------------------------------------------------------------------------
__global__ __launch_bounds__(256) void oproj_kernel(
    const __hip_bfloat16* __restrict__ o_in,
    const float* __restrict__ Wo,
    float* __restrict__ out)
{
    __shared__ __align__(16) char smem[24576];   // K-loop: As 16K + Bs 8K; epi: 64x68 fp32 (17.4K)
    short* As = (short*)smem;                    // 128 x 64
    short* Bs = As + 8192;                       // 64 x 64
    float* fpool = (float*)smem;

    const int m0 = blockIdx.x * 128;
    const int n0 = blockIdx.y * 64;

    const int t = threadIdx.x;
    const int lane = t & 63;
    const int w = t >> 6;
    const int quad = lane >> 4;
    const int ln = lane & 15;
    const int wm = (w >> 1) * 64;
    const int wn = (w & 1) * 32;

    floatx4 acc[4][2];
    #pragma unroll
    for (int i = 0; i < 4; i++)
        #pragma unroll
        for (int j = 0; j < 2; j++) acc[i][j] = (floatx4){0.f, 0.f, 0.f, 0.f};

    for (int k0 = 0; k0 < DM; k0 += 64) {
        #pragma unroll
        for (int it = 0; it < 4; it++) {
            int row = w * 32 + it * 8 + (lane >> 3);
            int sg = (lane & 7) ^ (row & 7);
            gl2lds16(&o_in[(size_t)(m0 + row) * DM + k0 + sg * 8], &As[(w * 32 + it * 8) * 64]);
        }
        #pragma unroll
        for (int p = 0; p < 2; p++) {
            int r = (t >> 3) + p * 32;
            int sg2 = t & 7;
            *reinterpret_cast<short8*>(&Bs[r * 64 + ((sg2 ^ (r & 7)) << 3)]) =
                load8_f32_as_bf16(&Wo[(size_t)(n0 + r) * DM + k0 + sg2 * 8]);
        }
        __syncthreads();

        short8 af[4][2], bfr[2][2];
        #pragma unroll
        for (int i = 0; i < 4; i++)
            #pragma unroll
            for (int kc = 0; kc < 2; kc++)
                af[i][kc] = *reinterpret_cast<const short8*>(
                    &As[(wm + i * 16 + ln) * 64 + (((kc * 4 + quad) ^ (ln & 7)) << 3)]);
        #pragma unroll
        for (int j = 0; j < 2; j++)
            #pragma unroll
            for (int kc = 0; kc < 2; kc++)
                bfr[j][kc] = *reinterpret_cast<const short8*>(
                    &Bs[(wn + j * 16 + ln) * 64 + (((kc * 4 + quad) ^ (ln & 7)) << 3)]);

        #pragma unroll
        for (int kc = 0; kc < 2; kc++)
            #pragma unroll
            for (int i = 0; i < 4; i++)
                #pragma unroll
                for (int j = 0; j < 2; j++)
                    acc[i][j] = __builtin_amdgcn_mfma_f32_16x16x32_bf16(
                        af[i][kc], bfr[j][kc], acc[i][j], 0, 0, 0);
        __syncthreads();
    }

    // Epilogue: two 64-row passes through fpool (pitch 68), coalesced stores.
    #pragma unroll
    for (int ph = 0; ph < 2; ph++) {
        if ((w >> 1) == ph) {
            #pragma unroll
            for (int j = 0; j < 2; j++)
                #pragma unroll
                for (int i = 0; i < 4; i++) {
                    int rl = i * 16 + quad * 4;
                    #pragma unroll
                    for (int r = 0; r < 4; r++)
                        fpool[(rl + r) * 68 + wn + j * 16 + ln] = acc[i][j][r];
                }
        }
        __syncthreads();
        int row = t >> 2;                        // 0..63
        int c0 = (t & 3) * 16;                   // 16 floats = 64 B per thread
        size_t gbase = (size_t)(m0 + ph * 64 + row) * DM + n0 + c0;
        #pragma unroll
        for (int c = 0; c < 4; c++)
            *reinterpret_cast<float4*>(&out[gbase + c * 4]) =
                *reinterpret_cast<const float4*>(&fpool[row * 68 + c0 + c * 4]);
        __syncthreads();
    }
}

extern "C" void kernel_launch(void* const* d_in, const int* in_sizes, int n_in,
                              void* d_out, int out_size, void* d_ws, size_t ws_size,
                              hipStream_t stream) {
    const float* x  = (const float*)d_in[0];
    const int* tp   = (const int*)d_in[1];
    const float* Wq = (const float*)d_in[2];
    const float* Wk = (const float*)d_in[3];
    const float* Wv = (const float*)d_in[4];
    const float* Wo = (const float*)d_in[5];
    float* out = (float*)d_out;

    char* ws = (char*)d_ws;
    const size_t MB = 1024 * 1024;
    __hip_bfloat16* xb    = (__hip_bfloat16*)(ws);              // 8 MB; reused as o_ws
    __hip_bfloat16* q_ws  = (__hip_bfloat16*)(ws + 8  * MB);    // [SEQ][DM]
    __hip_bfloat16* k_ws  = (__hip_bfloat16*)(ws + 16 * MB);    // [SEQ][DM]
    __hip_bfloat16* vt_ws = (__hip_bfloat16*)(ws + 24 * MB);    // [1024][SEQ]
    __hip_bfloat16* o_ws  = xb;
    __hip_bfloat16* Wqb = (__hip_bfloat16*)d_out;                // parked in d_out
    __hip_bfloat16* Wkb = Wqb + (size_t)DM * DM;
    __hip_bfloat16* Wvb = Wkb + (size_t)DM * DM;
    float2* tab = (float2*)((char*)d_out + 6 * MB);

    prep_kernel<<<4096, 256, 0, stream>>>(x, Wq, Wk, Wv, tp, xb, Wqb, Wkb, Wvb, tab);
    qkv_rope_kernel<<<dim3(32, 24), 256, 0, stream>>>(xb, tab, Wqb, Wkb, Wvb, q_ws, k_ws, vt_ws);
    attn_kernel<<<dim3(16, 16), 512, 0, stream>>>(q_ws, k_ws, vt_ws, o_ws);
    oproj_kernel<<<dim3(32, 16), 256, 0, stream>>>(o_ws, Wo, out);
}